// Round 3
// baseline (140.160 us; speedup 1.0000x reference)
//
#include <hip/hip_runtime.h>
#include <hip/hip_bf16.h>
#include <math.h>

// Problem: B=8192, D=1024, H=128, C=16
// out tuple: masked[B*D], mask_norm(0.0), embed_norm(||x||F), x[B*D]  -> f32
#define B_ 8192
#define D_ 1024
#define H_ 128
#define C_ 16
#define TM 64
#define MAXT (B_/TM + C_)   // 144 upper bound on tiles
#define BD (B_*D_)
#define KS 4                // K-split factor for layer 1
#define KSL (D_/KS)         // 256 K per slice

using bf16x8 = __attribute__((ext_vector_type(8))) __bf16;
using f32x4  = __attribute__((ext_vector_type(4))) float;
typedef unsigned short ushort_t;
using ushort8 = __attribute__((ext_vector_type(8))) ushort_t;

// ws layout (byte offsets):
//   0      counts[16]  int
//   64     cursor[16]  int
//   128    tC[144]     int   (int index 32)
//   704    tR[144]     int   (int index 176)
//   1280   tE[144]     int   (int index 320)
//   4096   sidx[8192]  int   (int index 1024)
//   36864  psum[8192*8] f32  (per-row, per-chunk sum-of-squares partials; 256 KiB)
//   299008 ep[16]       f32  (||x||^2 bucket accumulators)
//   303104 hpart bf16[4][8192*128]  (8 MiB; layer-1 K-slice partials)

__device__ inline bf16x8 cvt8(float4 a, float4 b) {
    bf16x8 r;
    r[0] = (__bf16)a.x; r[1] = (__bf16)a.y; r[2] = (__bf16)a.z; r[3] = (__bf16)a.w;
    r[4] = (__bf16)b.x; r[5] = (__bf16)b.y; r[6] = (__bf16)b.z; r[7] = (__bf16)b.w;
    return r;
}

__global__ void k_hist(const int* __restrict__ c, int* __restrict__ counts) {
    int b = blockIdx.x * 256 + threadIdx.x;
    atomicAdd(&counts[c[b]], 1);
}

__global__ void k_setup(int* __restrict__ w) {
    if (threadIdx.x != 0) return;
    int off = 0, nt = 0;
    for (int cc = 0; cc < C_; ++cc) {
        w[16 + cc] = off;            // cursor base for scatter
        int cnt = w[cc];
        for (int t = 0; t < cnt; t += TM) {
            w[32 + nt]  = cc;        // tile condition
            w[176 + nt] = off + t;   // tile first sorted position
            w[320 + nt] = off + cnt; // condition end
            ++nt;
        }
        off += cnt;
    }
    for (; nt < MAXT; ++nt) w[32 + nt] = -1;
}

__global__ void k_scatter(const int* __restrict__ c, int* __restrict__ cursor,
                          int* __restrict__ sidx) {
    int b = blockIdx.x * 256 + threadIdx.x;
    int pos = atomicAdd(&cursor[c[b]], 1);
    sidx[pos] = b;
}

// ---- Layer 1 (K-split): hpart[slice][p][j] = sum_{d in slice} x[sidx[p]][d] * W1[c][j][d]
// Also: copies its K-range of x -> out[BD+2 ...] and accumulates ||x||^2 partials.
__global__ __launch_bounds__(256) void k_l1(const float* __restrict__ x,
                                            const float* __restrict__ W1,
                                            const int* __restrict__ wsi,
                                            __bf16* __restrict__ hpart,
                                            float* __restrict__ out,
                                            float* __restrict__ ep) {
    int bid = blockIdx.x >> 2, slice = blockIdx.x & 3;
    int cond = wsi[32 + bid];
    if (cond < 0) return;
    int row0 = wsi[176 + bid], end = wsi[320 + bid];
    const int* sidx = wsi + 1024;

    __shared__ ushort_t As[TM * 32];    // 64 rows x 32 k (bf16), 16B-slot XOR swizzle
    __shared__ ushort_t Bs[H_ * 32];    // 128 rows x 32 k
    __shared__ float red[4];

    int tid = threadIdx.x;
    // A staging: 4 threads per row, 8 elems each
    int ar = tid >> 2, aslot = tid & 3;
    int p = row0 + ar;
    bool valid = (p < end);
    int srow = sidx[valid ? p : (end - 1)];
    const float* xrow = x + (size_t)srow * D_ + slice * KSL + aslot * 8;
    float* xcopy = out + (size_t)BD + 2 + (size_t)srow * D_ + slice * KSL + aslot * 8;
    ushort_t* awr = As + ar * 32 + ((aslot ^ (ar & 3)) * 8);
    // B staging: 2 threads per row, 16 elems each
    int br = tid >> 1, bhalf = tid & 1;
    const float* wrow = W1 + ((size_t)(cond * H_ + br)) * D_ + slice * KSL + bhalf * 16;
    int bs0 = bhalf * 2;
    ushort_t* bwr0 = Bs + br * 32 + (((bs0)     ^ (br & 3)) * 8);
    ushort_t* bwr1 = Bs + br * 32 + (((bs0 + 1) ^ (br & 3)) * 8);

    int wv = tid >> 6, lane = tid & 63;
    int l15 = lane & 15, kg = lane >> 4;
    int arow = wv * 16 + l15;
    const ushort_t* ard = As + arow * 32 + ((kg ^ (arow & 3)) * 8);

    // prime the software pipeline
    float4 a0  = *(const float4*)(xrow);
    float4 a1  = *(const float4*)(xrow + 4);
    float4 w0  = *(const float4*)(wrow);
    float4 w1v = *(const float4*)(wrow + 4);
    float4 w2v = *(const float4*)(wrow + 8);
    float4 w3v = *(const float4*)(wrow + 12);

    float xsq = 0.0f;
    f32x4 acc[8] = {};
    for (int k0 = 0; k0 < KSL; k0 += 32) {
        // prefetch next K-slab (wraps harmlessly on the last iteration)
        int kn = (k0 + 32) & (KSL - 1);
        float4 na0  = *(const float4*)(xrow + kn);
        float4 na1  = *(const float4*)(xrow + kn + 4);
        float4 nw0  = *(const float4*)(wrow + kn);
        float4 nw1v = *(const float4*)(wrow + kn + 4);
        float4 nw2v = *(const float4*)(wrow + kn + 8);
        float4 nw3v = *(const float4*)(wrow + kn + 12);

        __syncthreads();   // previous iteration's LDS reads done
        *(bf16x8*)awr  = cvt8(a0, a1);
        *(bf16x8*)bwr0 = cvt8(w0, w1v);
        *(bf16x8*)bwr1 = cvt8(w2v, w3v);
        // x copy + ||x||^2 while the data is in registers
        if (valid) {
            float2* xo = (float2*)(xcopy + k0);
            xo[0] = make_float2(a0.x, a0.y);
            xo[1] = make_float2(a0.z, a0.w);
            xo[2] = make_float2(a1.x, a1.y);
            xo[3] = make_float2(a1.z, a1.w);
            xsq += a0.x*a0.x + a0.y*a0.y + a0.z*a0.z + a0.w*a0.w
                 + a1.x*a1.x + a1.y*a1.y + a1.z*a1.z + a1.w*a1.w;
        }
        __syncthreads();
        bf16x8 af = *(const bf16x8*)ard;
#pragma unroll
        for (int n = 0; n < 8; ++n) {
            int brow = n * 16 + l15;
            bf16x8 bf = *(const bf16x8*)(Bs + brow * 32 + ((kg ^ (brow & 3)) * 8));
            acc[n] = __builtin_amdgcn_mfma_f32_16x16x32_bf16(af, bf, acc[n], 0, 0, 0);
        }
        a0 = na0; a1 = na1; w0 = nw0; w1v = nw1v; w2v = nw2v; w3v = nw3v;
    }
    // epilogue: store bf16 partial h by (slice, sorted position); bias added in k_l2
    __bf16* hout = hpart + (size_t)slice * (B_ * H_);
#pragma unroll
    for (int n = 0; n < 8; ++n) {
        int j = n * 16 + l15;
#pragma unroll
        for (int v = 0; v < 4; ++v) {
            int pr = row0 + wv * 16 + kg * 4 + v;
            if (pr < end) hout[(size_t)pr * H_ + j] = (__bf16)acc[n][v];
        }
    }
    // block-reduce ||x||^2 partials -> one atomic per block into 16 buckets
    float s = xsq;
    s += __shfl_xor(s, 1);  s += __shfl_xor(s, 2);  s += __shfl_xor(s, 4);
    s += __shfl_xor(s, 8);  s += __shfl_xor(s, 16); s += __shfl_xor(s, 32);
    if (lane == 0) red[wv] = s;
    __syncthreads();
    if (tid == 0) atomicAdd(&ep[blockIdx.x & 15], red[0] + red[1] + red[2] + red[3]);
}

// ---- Layer 2: out[b][jg] = sum_k h[p][k] * W2[c][jg][k] + b2[c][jg]; psum per (row,chunk) ----
__global__ __launch_bounds__(256) void k_l2(const __bf16* __restrict__ hpart,
                                            const float* __restrict__ W2,
                                            const float* __restrict__ b1,
                                            const float* __restrict__ b2,
                                            const int* __restrict__ wsi,
                                            float* __restrict__ psum,
                                            float* __restrict__ out) {
    int tile = blockIdx.x >> 3, nch = blockIdx.x & 7;
    int cond = wsi[32 + tile];
    if (cond < 0) return;
    int row0 = wsi[176 + tile], end = wsi[320 + tile];
    const int* sidx = wsi + 1024;

    __shared__ ushort_t Hs[TM * 128];    // 64 x 128 bf16
    __shared__ ushort_t Ws[128 * 128];   // 128 out-cols x 128 k bf16

    int tid = threadIdx.x;
    {   // Hs staging: 4 threads/row, 4 slots of 8 bf16 each; sum 4 K-slice partials + b1
        int r = tid >> 2;
        int pp = row0 + r; int pc = pp < end ? pp : (end - 1);
        const ushort_t* src = (const ushort_t*)hpart + (size_t)pc * H_ + (tid & 3) * 32;
        int jb = (tid & 3) * 32;
        int s0 = (tid & 3) * 4;
#pragma unroll
        for (int s = 0; s < 4; ++s) {
            bf16x8 v0 = *(const bf16x8*)(src + s * 8);
            bf16x8 v1 = *(const bf16x8*)(src + (size_t)(B_ * H_)     + s * 8);
            bf16x8 v2 = *(const bf16x8*)(src + (size_t)(B_ * H_) * 2 + s * 8);
            bf16x8 v3 = *(const bf16x8*)(src + (size_t)(B_ * H_) * 3 + s * 8);
            bf16x8 o;
#pragma unroll
            for (int e = 0; e < 8; ++e) {
                float sum = (float)v0[e] + (float)v1[e] + (float)v2[e] + (float)v3[e]
                          + b1[cond * H_ + jb + s * 8 + e];
                o[e] = (__bf16)sum;
            }
            *(bf16x8*)(Hs + r * 128 + (((s0 + s) ^ (r & 15)) * 8)) = o;
        }
    }
    {   // Ws staging: 2 threads/row, 64 f32 each -> bf16
        int r = tid >> 1;
        const float* src = W2 + ((size_t)(cond * D_ + nch * 128 + r)) * H_ + (tid & 1) * 64;
        int s0 = (tid & 1) * 8;
#pragma unroll
        for (int s = 0; s < 8; ++s) {
            float4 f0 = *(const float4*)(src + s * 8);
            float4 f1 = *(const float4*)(src + s * 8 + 4);
            *(bf16x8*)(Ws + r * 128 + (((s0 + s) ^ (r & 15)) * 8)) = cvt8(f0, f1);
        }
    }
    __syncthreads();

    int wv = tid >> 6, lane = tid & 63, l15 = lane & 15, kg = lane >> 4;
    int hr = wv * 16 + l15;
    f32x4 acc[8] = {};
#pragma unroll
    for (int ks = 0; ks < 4; ++ks) {
        bf16x8 af = *(const bf16x8*)(Hs + hr * 128 + (((ks * 4 + kg) ^ (hr & 15)) * 8));
#pragma unroll
        for (int n = 0; n < 8; ++n) {
            int wr = n * 16 + l15;
            bf16x8 bf = *(const bf16x8*)(Ws + wr * 128 + (((ks * 4 + kg) ^ (wr & 15)) * 8));
            acc[n] = __builtin_amdgcn_mfma_f32_16x16x32_bf16(af, bf, acc[n], 0, 0, 0);
        }
    }
    // epilogue
    int bbs[4];
#pragma unroll
    for (int v = 0; v < 4; ++v) {
        int pr = row0 + wv * 16 + kg * 4 + v;
        bbs[v] = (pr < end) ? sidx[pr] : -1;
    }
    float sq[4] = {0.f, 0.f, 0.f, 0.f};
    int jbase = nch * 128;
#pragma unroll
    for (int n = 0; n < 8; ++n) {
        int jg = jbase + n * 16 + l15;
        float bias = b2[cond * D_ + jg];
#pragma unroll
        for (int v = 0; v < 4; ++v) {
            float val = acc[n][v] + bias;
            if (bbs[v] >= 0) out[(size_t)bbs[v] * D_ + jg] = val;
            sq[v] += val * val;
        }
    }
#pragma unroll
    for (int v = 0; v < 4; ++v) {
        float s = sq[v];
        s += __shfl_xor(s, 1);
        s += __shfl_xor(s, 2);
        s += __shfl_xor(s, 4);
        s += __shfl_xor(s, 8);
        if (l15 == 0 && bbs[v] >= 0) psum[bbs[v] * 8 + nch] = s;   // written exactly once
    }
}

// ---- normalize masked rows (4 rows per block, no atomics) ----
__global__ __launch_bounds__(256) void k_norm(const float* __restrict__ psum,
                                              float* __restrict__ out) {
    int row = blockIdx.x * 4 + (threadIdx.x >> 6);
    int lane = threadIdx.x & 63;
    float s = 0.0f;
#pragma unroll
    for (int i = 0; i < 8; ++i) s += psum[row * 8 + i];
    float inv = 1.0f / (sqrtf(s) + 1e-10f);
    float4* po = (float4*)out + (size_t)row * 256 + lane;
#pragma unroll
    for (int i = 0; i < 4; ++i) {
        float4 v = po[i * 64];
        v.x *= inv; v.y *= inv; v.z *= inv; v.w *= inv;
        po[i * 64] = v;
    }
}

__global__ void k_fin(const float* __restrict__ ep, float* __restrict__ out) {
    float s = 0.0f;
#pragma unroll
    for (int i = 0; i < 16; ++i) s += ep[i];
    out[BD] = 0.0f;
    out[BD + 1] = sqrtf(s);
}

extern "C" void kernel_launch(void* const* d_in, const int* in_sizes, int n_in,
                              void* d_out, int out_size, void* d_ws, size_t ws_size,
                              hipStream_t stream) {
    const float* x  = (const float*)d_in[0];
    const int*   c  = (const int*)d_in[1];
    const float* W1 = (const float*)d_in[2];
    const float* b1 = (const float*)d_in[3];
    const float* W2 = (const float*)d_in[4];
    const float* b2 = (const float*)d_in[5];
    float* out = (float*)d_out;
    char* ws = (char*)d_ws;
    int* wsi = (int*)ws;
    float* psum   = (float*)(ws + 36864);
    float* ep     = (float*)(ws + 299008);
    __bf16* hpart = (__bf16*)(ws + 303104);

    hipMemsetAsync(ws, 0, 128, stream);          // counts + cursor
    hipMemsetAsync(ws + 299008, 0, 64, stream);  // ep[16]

    k_hist<<<B_ / 256, 256, 0, stream>>>(c, wsi);
    k_setup<<<1, 1, 0, stream>>>(wsi);
    k_scatter<<<B_ / 256, 256, 0, stream>>>(c, wsi + 16, wsi + 1024);
    k_l1<<<MAXT * KS, 256, 0, stream>>>(x, W1, wsi, hpart, out, ep);
    k_l2<<<MAXT * 8, 256, 0, stream>>>(hpart, W2, b1, b2, wsi, psum, out);
    k_norm<<<B_ / 4, 256, 0, stream>>>(psum, out);
    k_fin<<<1, 1, 0, stream>>>(ep, out);
}

// Round 4
// 88.520 us; speedup vs baseline: 1.5834x; 1.5834x over previous
//
#include <hip/hip_runtime.h>
#include <hip/hip_bf16.h>
#include <math.h>

// Problem: B=8192, D=1024, H=128, C=16
// out tuple: masked[B*D], mask_norm(0.0), embed_norm(||x||F), x[B*D]  -> f32
#define B_ 8192
#define D_ 1024
#define H_ 128
#define C_ 16
#define TM 64
#define MAXT (B_/TM + C_)   // 144 upper bound on tiles
#define BD (B_*D_)
#define KS 4                // K-split factor for layer 1
#define KSL (D_/KS)         // 256 K per slice
#define NCH 16              // layer-2 column chunks (64 cols each)

using bf16x8 = __attribute__((ext_vector_type(8))) __bf16;
using f32x4  = __attribute__((ext_vector_type(4))) float;
typedef unsigned short ushort_t;
using ushort8 = __attribute__((ext_vector_type(8))) ushort_t;

// ws layout (byte offsets):
//   0       counts/cursor scratch (legacy, unused)
//   128     tC[144]   int (int idx 32)
//   704     tR[144]   int (int idx 176)
//   1280    tE[144]   int (int idx 320)
//   4096    sidx[8192] int (int idx 1024)
//   36864   psum[8192*16] f32 (512 KiB)
//   561152  ep[16]    f32
//   565248  hpart bf16[4][8192*128]  (8 MiB)

__device__ inline bf16x8 cvt8(float4 a, float4 b) {
    bf16x8 r;
    r[0] = (__bf16)a.x; r[1] = (__bf16)a.y; r[2] = (__bf16)a.z; r[3] = (__bf16)a.w;
    r[4] = (__bf16)b.x; r[5] = (__bf16)b.y; r[6] = (__bf16)b.z; r[7] = (__bf16)b.w;
    return r;
}

// ---- fused histogram + tile table + scatter (single block), also zeroes ep ----
__global__ __launch_bounds__(1024) void k_sort(const int* __restrict__ c,
                                               int* __restrict__ w,
                                               float* __restrict__ ep) {
    __shared__ int hist[C_];
    __shared__ int base[C_];
    int tid = threadIdx.x;
    if (tid < C_) { hist[tid] = 0; ep[tid] = 0.0f; }
    __syncthreads();
    int myc[8];
#pragma unroll
    for (int i = 0; i < 8; ++i) {
        myc[i] = c[tid * 8 + i];
        atomicAdd(&hist[myc[i]], 1);
    }
    __syncthreads();
    if (tid == 0) {
        int off = 0, nt = 0;
        for (int cc = 0; cc < C_; ++cc) {
            int cnt = hist[cc];
            base[cc] = off;
            for (int t = 0; t < cnt; t += TM) {
                w[32 + nt]  = cc;
                w[176 + nt] = off + t;
                w[320 + nt] = off + cnt;
                ++nt;
            }
            off += cnt;
        }
        for (; nt < MAXT; ++nt) w[32 + nt] = -1;
    }
    __syncthreads();
#pragma unroll
    for (int i = 0; i < 8; ++i) {
        int pos = atomicAdd(&base[myc[i]], 1);
        w[1024 + pos] = tid * 8 + i;
    }
}

// ---- Layer 1 (K-split): hpart[slice][p][j] = sum_{d in slice} x[sidx[p]][d] * W1[c][j][d]
// Also: copies its K-range of x -> out[BD+2 ...] and accumulates ||x||^2 partials.
__global__ __launch_bounds__(256) void k_l1(const float* __restrict__ x,
                                            const float* __restrict__ W1,
                                            const int* __restrict__ wsi,
                                            __bf16* __restrict__ hpart,
                                            float* __restrict__ out,
                                            float* __restrict__ ep) {
    int bid = blockIdx.x >> 2, slice = blockIdx.x & 3;
    int cond = wsi[32 + bid];
    if (cond < 0) return;
    int row0 = wsi[176 + bid], end = wsi[320 + bid];
    const int* sidx = wsi + 1024;

    __shared__ ushort_t As[TM * 32];
    __shared__ ushort_t Bs[H_ * 32];
    __shared__ float red[4];

    int tid = threadIdx.x;
    int ar = tid >> 2, aslot = tid & 3;
    int p = row0 + ar;
    bool valid = (p < end);
    int srow = sidx[valid ? p : (end - 1)];
    const float* xrow = x + (size_t)srow * D_ + slice * KSL + aslot * 8;
    float* xcopy = out + (size_t)BD + 2 + (size_t)srow * D_ + slice * KSL + aslot * 8;
    ushort_t* awr = As + ar * 32 + ((aslot ^ (ar & 3)) * 8);
    int br = tid >> 1, bhalf = tid & 1;
    const float* wrow = W1 + ((size_t)(cond * H_ + br)) * D_ + slice * KSL + bhalf * 16;
    int bs0 = bhalf * 2;
    ushort_t* bwr0 = Bs + br * 32 + (((bs0)     ^ (br & 3)) * 8);
    ushort_t* bwr1 = Bs + br * 32 + (((bs0 + 1) ^ (br & 3)) * 8);

    int wv = tid >> 6, lane = tid & 63;
    int l15 = lane & 15, kg = lane >> 4;
    int arow = wv * 16 + l15;
    const ushort_t* ard = As + arow * 32 + ((kg ^ (arow & 3)) * 8);

    float4 a0  = *(const float4*)(xrow);
    float4 a1  = *(const float4*)(xrow + 4);
    float4 w0  = *(const float4*)(wrow);
    float4 w1v = *(const float4*)(wrow + 4);
    float4 w2v = *(const float4*)(wrow + 8);
    float4 w3v = *(const float4*)(wrow + 12);

    float xsq = 0.0f;
    f32x4 acc[8] = {};
    for (int k0 = 0; k0 < KSL; k0 += 32) {
        int kn = (k0 + 32) & (KSL - 1);
        float4 na0  = *(const float4*)(xrow + kn);
        float4 na1  = *(const float4*)(xrow + kn + 4);
        float4 nw0  = *(const float4*)(wrow + kn);
        float4 nw1v = *(const float4*)(wrow + kn + 4);
        float4 nw2v = *(const float4*)(wrow + kn + 8);
        float4 nw3v = *(const float4*)(wrow + kn + 12);

        __syncthreads();
        *(bf16x8*)awr  = cvt8(a0, a1);
        *(bf16x8*)bwr0 = cvt8(w0, w1v);
        *(bf16x8*)bwr1 = cvt8(w2v, w3v);
        if (valid) {
            float2* xo = (float2*)(xcopy + k0);
            xo[0] = make_float2(a0.x, a0.y);
            xo[1] = make_float2(a0.z, a0.w);
            xo[2] = make_float2(a1.x, a1.y);
            xo[3] = make_float2(a1.z, a1.w);
            xsq += a0.x*a0.x + a0.y*a0.y + a0.z*a0.z + a0.w*a0.w
                 + a1.x*a1.x + a1.y*a1.y + a1.z*a1.z + a1.w*a1.w;
        }
        __syncthreads();
        bf16x8 af = *(const bf16x8*)ard;
#pragma unroll
        for (int n = 0; n < 8; ++n) {
            int brow = n * 16 + l15;
            bf16x8 bf = *(const bf16x8*)(Bs + brow * 32 + ((kg ^ (brow & 3)) * 8));
            acc[n] = __builtin_amdgcn_mfma_f32_16x16x32_bf16(af, bf, acc[n], 0, 0, 0);
        }
        a0 = na0; a1 = na1; w0 = nw0; w1v = nw1v; w2v = nw2v; w3v = nw3v;
    }
    __bf16* hout = hpart + (size_t)slice * (B_ * H_);
#pragma unroll
    for (int n = 0; n < 8; ++n) {
        int j = n * 16 + l15;
#pragma unroll
        for (int v = 0; v < 4; ++v) {
            int pr = row0 + wv * 16 + kg * 4 + v;
            if (pr < end) hout[(size_t)pr * H_ + j] = (__bf16)acc[n][v];
        }
    }
    float s = xsq;
    s += __shfl_xor(s, 1);  s += __shfl_xor(s, 2);  s += __shfl_xor(s, 4);
    s += __shfl_xor(s, 8);  s += __shfl_xor(s, 16); s += __shfl_xor(s, 32);
    if (lane == 0) red[wv] = s;
    __syncthreads();
    if (tid == 0) atomicAdd(&ep[blockIdx.x & 15], red[0] + red[1] + red[2] + red[3]);
}

// ---- Layer 2: 64-col chunks; out + per-(row,chunk) sumsq partial ----
__global__ __launch_bounds__(256) void k_l2(const __bf16* __restrict__ hpart,
                                            const float* __restrict__ W2,
                                            const float* __restrict__ b1,
                                            const float* __restrict__ b2,
                                            const int* __restrict__ wsi,
                                            float* __restrict__ psum,
                                            float* __restrict__ out) {
    int tile = blockIdx.x >> 4, nch = blockIdx.x & 15;
    int cond = wsi[32 + tile];
    if (cond < 0) return;
    int row0 = wsi[176 + tile], end = wsi[320 + tile];
    const int* sidx = wsi + 1024;
    int jbase = nch * 64;

    __shared__ ushort_t Hs[TM * 128];   // 64 rows x 128 k bf16 (16 KB)
    __shared__ ushort_t Ws[64 * 128];   // 64 out-cols x 128 k bf16 (16 KB)

    int tid = threadIdx.x;
    {   // Hs staging: 4 threads/row, 4 slots of 8; sum 4 K-slice partials + b1
        int r = tid >> 2;
        int pp = row0 + r; int pc = pp < end ? pp : (end - 1);
        const ushort_t* src = (const ushort_t*)hpart + (size_t)pc * H_ + (tid & 3) * 32;
        int jb = (tid & 3) * 32;
        int s0 = (tid & 3) * 4;
#pragma unroll
        for (int s = 0; s < 4; ++s) {
            bf16x8 v0 = *(const bf16x8*)(src + s * 8);
            bf16x8 v1 = *(const bf16x8*)(src + (size_t)(B_ * H_)     + s * 8);
            bf16x8 v2 = *(const bf16x8*)(src + (size_t)(B_ * H_) * 2 + s * 8);
            bf16x8 v3 = *(const bf16x8*)(src + (size_t)(B_ * H_) * 3 + s * 8);
            bf16x8 o;
#pragma unroll
            for (int e = 0; e < 8; ++e) {
                float sum = (float)v0[e] + (float)v1[e] + (float)v2[e] + (float)v3[e]
                          + b1[cond * H_ + jb + s * 8 + e];
                o[e] = (__bf16)sum;
            }
            *(bf16x8*)(Hs + r * 128 + (((s0 + s) ^ (r & 15)) * 8)) = o;
        }
    }
    {   // Ws staging: 64 out-cols, 4 threads/col, 4 slots of 8 f32->bf16
        int r = tid >> 2;
        const float* src = W2 + ((size_t)(cond * D_ + jbase + r)) * H_ + (tid & 3) * 32;
        int s0 = (tid & 3) * 4;
#pragma unroll
        for (int s = 0; s < 4; ++s) {
            float4 f0 = *(const float4*)(src + s * 8);
            float4 f1 = *(const float4*)(src + s * 8 + 4);
            *(bf16x8*)(Ws + r * 128 + (((s0 + s) ^ (r & 15)) * 8)) = cvt8(f0, f1);
        }
    }
    __syncthreads();

    int wv = tid >> 6, lane = tid & 63, l15 = lane & 15, kg = lane >> 4;
    int hr = wv * 16 + l15;
    f32x4 acc[4] = {};
#pragma unroll
    for (int ks = 0; ks < 4; ++ks) {
        bf16x8 af = *(const bf16x8*)(Hs + hr * 128 + (((ks * 4 + kg) ^ (hr & 15)) * 8));
#pragma unroll
        for (int n = 0; n < 4; ++n) {
            int wr = n * 16 + l15;
            bf16x8 bf = *(const bf16x8*)(Ws + wr * 128 + (((ks * 4 + kg) ^ (wr & 15)) * 8));
            acc[n] = __builtin_amdgcn_mfma_f32_16x16x32_bf16(af, bf, acc[n], 0, 0, 0);
        }
    }
    int bbs[4];
#pragma unroll
    for (int v = 0; v < 4; ++v) {
        int pr = row0 + wv * 16 + kg * 4 + v;
        bbs[v] = (pr < end) ? sidx[pr] : -1;
    }
    float sq[4] = {0.f, 0.f, 0.f, 0.f};
#pragma unroll
    for (int n = 0; n < 4; ++n) {
        int jg = jbase + n * 16 + l15;
        float bias = b2[cond * D_ + jg];
#pragma unroll
        for (int v = 0; v < 4; ++v) {
            float val = acc[n][v] + bias;
            if (bbs[v] >= 0) out[(size_t)bbs[v] * D_ + jg] = val;
            sq[v] += val * val;
        }
    }
#pragma unroll
    for (int v = 0; v < 4; ++v) {
        float s = sq[v];
        s += __shfl_xor(s, 1);
        s += __shfl_xor(s, 2);
        s += __shfl_xor(s, 4);
        s += __shfl_xor(s, 8);
        if (l15 == 0 && bbs[v] >= 0) psum[bbs[v] * NCH + nch] = s;
    }
}

// ---- normalize masked rows (4 rows per block, no atomics) ----
__global__ __launch_bounds__(256) void k_norm(const float* __restrict__ psum,
                                              float* __restrict__ out) {
    int row = blockIdx.x * 4 + (threadIdx.x >> 6);
    int lane = threadIdx.x & 63;
    float s = 0.0f;
#pragma unroll
    for (int i = 0; i < NCH; ++i) s += psum[row * NCH + i];
    float inv = 1.0f / (sqrtf(s) + 1e-10f);
    float4* po = (float4*)out + (size_t)row * 256 + lane;
#pragma unroll
    for (int i = 0; i < 4; ++i) {
        float4 v = po[i * 64];
        v.x *= inv; v.y *= inv; v.z *= inv; v.w *= inv;
        po[i * 64] = v;
    }
}

__global__ void k_fin(const float* __restrict__ ep, float* __restrict__ out) {
    float s = 0.0f;
#pragma unroll
    for (int i = 0; i < 16; ++i) s += ep[i];
    out[BD] = 0.0f;
    out[BD + 1] = sqrtf(s);
}

extern "C" void kernel_launch(void* const* d_in, const int* in_sizes, int n_in,
                              void* d_out, int out_size, void* d_ws, size_t ws_size,
                              hipStream_t stream) {
    const float* x  = (const float*)d_in[0];
    const int*   c  = (const int*)d_in[1];
    const float* W1 = (const float*)d_in[2];
    const float* b1 = (const float*)d_in[3];
    const float* W2 = (const float*)d_in[4];
    const float* b2 = (const float*)d_in[5];
    float* out = (float*)d_out;
    char* ws = (char*)d_ws;
    int* wsi = (int*)ws;
    float* psum   = (float*)(ws + 36864);
    float* ep     = (float*)(ws + 561152);
    __bf16* hpart = (__bf16*)(ws + 565248);

    k_sort<<<1, 1024, 0, stream>>>(c, wsi, ep);
    k_l1<<<MAXT * KS, 256, 0, stream>>>(x, W1, wsi, hpart, out, ep);
    k_l2<<<MAXT * NCH, 256, 0, stream>>>(hpart, W2, b1, b2, wsi, psum, out);
    k_norm<<<B_ / 4, 256, 0, stream>>>(psum, out);
    k_fin<<<1, 1, 0, stream>>>(ep, out);
}